// Round 5
// baseline (298.532 us; speedup 1.0000x reference)
//
#include <hip/hip_runtime.h>

#define Bb_ 4
#define Hh_ 16
#define Ss_ 1024
#define DH 64
#define MAXLEN 2048
#define BH (Bb_*Hh_)
#define LDST 72   // 64 + 8 pad (bf16 elems)

typedef __attribute__((ext_vector_type(8))) short short8;
typedef __attribute__((ext_vector_type(4))) float floatx4;
typedef __attribute__((ext_vector_type(4))) unsigned short ushort4v;

// Cross-kernel scratch as device globals: load-time allocated, no dependence
// on ws_size (R17's split was confounded by a possible fallback). Rewritten
// by vote_kernel on every replay before emit_kernel reads them.
__device__ int   g_flags[512];
__device__ float g_cvals[64 * 1024];

static __device__ __forceinline__ unsigned short f2bf(float f) {
    unsigned int u = __builtin_bit_cast(unsigned int, f);
    u = (u + 0x7fffu + ((u >> 16) & 1u)) >> 16;   // RNE
    return (unsigned short)u;
}

// Stage a 128x64 fp32 tile (row stride 64) -> bf16 LDS tile (row stride LDST)
static __device__ __forceinline__ void stage_tile(unsigned short* lds,
                                                  const float* __restrict__ g,
                                                  int tid) {
#pragma unroll
    for (int it = 0; it < 8; ++it) {
        int idx = it * 1024 + tid * 4;
        int row = idx >> 6, col = idx & 63;
        const float4 v = *reinterpret_cast<const float4*>(g + row * 64 + col);
        ushort4v o = { f2bf(v.x), f2bf(v.y), f2bf(v.z), f2bf(v.w) };
        *reinterpret_cast<ushort4v*>(lds + row * LDST + col) = o;
    }
}

// ===========================================================================
// R18. Kernel A (vote): unchanged from R17 — block (bh,j) votes on its 128
// ctx rows against the top-32 k rows (partial>=4096 => ctx clips to 2046
// exactly; nonneg terms make this sound regardless of remaining tiles) and
// writes the per-row constants c[bh][s] = q[s].tb[2046].
// Kernel B (emit): FILL-ISOMORPHIC dense store front. Thread writes float4
// at flat index it*524288 + gtid: per iteration the whole grid covers one
// contiguous 8 MB span (block bx owns row it*2048+bx), marching across the
// full 256 MB output. Per-block row constants are 32 uniform loads hoisted
// ahead of the loop -> the store loop is pure stores, structurally identical
// to __amd_rocclr_fillBufferAligned (which achieves 6.3 TB/s on this very
// buffer). This is the decisive test: per-block-contiguous (R17) vs
// device-dense (R18) — if both saturate equally, stores are exonerated.
// ===========================================================================

__global__ __launch_bounds__(256, 2)
void vote_kernel(const float* __restrict__ q, const float* __restrict__ k,
                 const float* __restrict__ tb) {
    __shared__ __align__(16) unsigned short Ab[128 * LDST];
    __shared__ __align__(16) unsigned short Kb[32 * LDST];
    __shared__ __align__(16) float sh_pr[64];
    __shared__ int shf[4];

    int bx = blockIdx.x;
    int bh = bx >> 3, j = bx & 7;
    int tid = threadIdx.x;
    int lane = tid & 63, w = tid >> 6;
    int lo = lane & 15, quad = lane >> 4;

    const float* kb = k + (size_t)bh * Ss_ * DH;
    const float* qb = q + (size_t)bh * Ss_ * DH;
    const float kSig = -0.18033688011112042f;  // -(1/8)*log2(e)

    {   // stage k rows [992,1024) -> Kb
        const float* ktop = kb + (size_t)992 * DH;
#pragma unroll
        for (int it = 0; it < 2; ++it) {
            int idx = it * 1024 + tid * 4;
            int row = idx >> 6, col = idx & 63;
            const float4 v = *reinterpret_cast<const float4*>(ktop + row * 64 + col);
            ushort4v o = { f2bf(v.x), f2bf(v.y), f2bf(v.z), f2bf(v.w) };
            *reinterpret_cast<ushort4v*>(Kb + row * LDST + col) = o;
        }
    }
    stage_tile(Ab, qb + (size_t)j * 128 * DH, tid);
    if (tid < 16) {
        int d0 = tid * 4;
        *reinterpret_cast<float4*>(&sh_pr[d0]) =
            *reinterpret_cast<const float4*>(tb + (size_t)(MAXLEN - 2) * DH + d0);
    }
    __syncthreads();

    short8 bkr[2][2];
#pragma unroll
    for (int j2 = 0; j2 < 2; ++j2) {
        bkr[j2][0] = *reinterpret_cast<const short8*>(
            &Kb[(j2 * 16 + lo) * LDST + 0 + quad * 8]);
        bkr[j2][1] = *reinterpret_cast<const short8*>(
            &Kb[(j2 * 16 + lo) * LDST + 32 + quad * 8]);
    }
    short8 afr[2][2];
#pragma unroll
    for (int i = 0; i < 2; ++i)
#pragma unroll
        for (int k2 = 0; k2 < 2; ++k2)
            afr[i][k2] = *reinterpret_cast<const short8*>(
                &Ab[(w * 32 + i * 16 + lo) * LDST + k2 * 32 + quad * 8]);

    float ps[2][4];
#pragma unroll
    for (int i = 0; i < 2; ++i)
#pragma unroll
        for (int r = 0; r < 4; ++r) ps[i][r] = 0.f;

#pragma unroll
    for (int j2 = 0; j2 < 2; ++j2) {
        float tcol = (float)(992 + j2 * 16 + lo);
#pragma unroll
        for (int i = 0; i < 2; ++i) {
            floatx4 c = {0.f, 0.f, 0.f, 0.f};
            c = __builtin_amdgcn_mfma_f32_16x16x32_bf16(afr[i][0], bkr[j2][0], c, 0, 0, 0);
            c = __builtin_amdgcn_mfma_f32_16x16x32_bf16(afr[i][1], bkr[j2][1], c, 0, 0, 0);
#pragma unroll
            for (int r = 0; r < 4; ++r) {
                float e = __builtin_amdgcn_exp2f(c[r] * kSig);
                float g = __builtin_amdgcn_rcpf(1.0f + e);
                ps[i][r] = fmaf(g, tcol, ps[i][r]);
            }
        }
    }

    bool ok = true;
#pragma unroll
    for (int i = 0; i < 2; ++i)
#pragma unroll
        for (int r = 0; r < 4; ++r) {
            float v = ps[i][r];
            v += __shfl_xor(v, 1);
            v += __shfl_xor(v, 2);
            v += __shfl_xor(v, 4);
            v += __shfl_xor(v, 8);
            ok = ok && (v >= 4096.0f);   // margin over 2046 vs bf16 error
        }
    int wall = __all(ok);
    if (lane == 0) shf[w] = wall;
    __syncthreads();
    if (tid == 0) g_flags[bx] = (shf[0] & shf[1] & shf[2] & shf[3]) & 1;

    // per-row constants c = q[row].e2046 (fp32, bit-identical to R16/R17)
    {
        int half = tid & 1;
        float ph[32];
#pragma unroll
        for (int d = 0; d < 32; ++d) ph[d] = sh_pr[half * 32 + d];
        int row = tid >> 1;
        const float* qr = qb + (size_t)(j * 128 + row) * DH + half * 32;
        float s = 0.f;
#pragma unroll
        for (int d = 0; d < 32; d += 4) {
            const float4 qq = *reinterpret_cast<const float4*>(qr + d);
            s += qq.x * ph[d] + qq.y * ph[d + 1] + qq.z * ph[d + 2] +
                 qq.w * ph[d + 3];
        }
        s += __shfl_xor(s, 1);
        if (half == 0) g_cvals[(bh << 10) + j * 128 + row] = s;
    }
}

__global__ __launch_bounds__(256)
void emit_kernel(const float* __restrict__ q, const float* __restrict__ k,
                 const float* __restrict__ tb, float* __restrict__ out) {
    __shared__ __align__(16) float sh[5120];  // 20 KB: slow path only
    __shared__ int wok[4];
    float* kch   = sh;            // 2048 f: 32x64 k chunk
    float* embch = sh + 2048;     // 2048 f: 32x64 emb chunk
    float* ctxv  = sh + 4096;     // 1024 f: ctx

    int bx = blockIdx.x;
    int tid = threadIdx.x;
    int lane = tid & 63, w = tid >> 6;

    // device-wide fast/slow decision (uniform: all blocks read same flags)
    int myok = g_flags[tid] & g_flags[tid + 256];
    unsigned long long bl = __ballot(myok != 0);
    if (lane == 0) wok[w] = (bl == ~0ull) ? 1 : 0;
    __syncthreads();
    int fast = wok[0] & wok[1] & wok[2] & wok[3];

    if (fast) {
        // Dense marching front: iteration it writes row (it*2048 + bx);
        // across the grid each iteration covers one contiguous 8 MB span.
        float cv[32];
#pragma unroll
        for (int it = 0; it < 32; ++it) cv[it] = g_cvals[it * 2048 + bx];
        float* po = out + (size_t)bx * 1024 + (size_t)(tid * 4);
#pragma unroll
        for (int it = 0; it < 32; ++it) {
            floatx4 vv = {cv[it], cv[it], cv[it], cv[it]};
            *reinterpret_cast<floatx4*>(po + (size_t)it * (2048 * 1024)) = vv;
        }
        return;
    }

    // ---- SLOW (exact; not taken on bench data): blocks 0..1023 ----------
    if (bx >= 1024) return;
    int bh = bx >> 4, m = bx & 15;
    const float* qb = q + (size_t)bh * Ss_ * DH;
    const float* kb = k + (size_t)bh * Ss_ * DH;
    const float kSig = -0.18033688011112042f;
    int r0 = m * 64;

    // 1) ctx[u] for ALL 1024 u, fp32 exact
#pragma unroll 1
    for (int p = 0; p < 4; ++p) {
        int u = p * 256 + tid;
        float4 qr[16];
#pragma unroll
        for (int d = 0; d < 16; ++d)
            qr[d] = *reinterpret_cast<const float4*>(qb + (size_t)u * DH + d * 4);
        float acc = 0.f;
#pragma unroll 1
        for (int ch = 0; ch < 32; ++ch) {
            __syncthreads();
            {
                int idx = tid * 8;
                const float4 a = *reinterpret_cast<const float4*>(
                    kb + (size_t)ch * 32 * DH + idx);
                const float4 b = *reinterpret_cast<const float4*>(
                    kb + (size_t)ch * 32 * DH + idx + 4);
                *reinterpret_cast<float4*>(kch + idx) = a;
                *reinterpret_cast<float4*>(kch + idx + 4) = b;
            }
            __syncthreads();
#pragma unroll
            for (int tt = 0; tt < 32; ++tt) {
                const float* kr = kch + tt * 64;
                float d = 0.f;
#pragma unroll
                for (int e = 0; e < 16; ++e) {
                    const float4 kk = *reinterpret_cast<const float4*>(kr + e * 4);
                    d += qr[e].x * kk.x + qr[e].y * kk.y + qr[e].z * kk.z +
                         qr[e].w * kk.w;
                }
                float ex = __builtin_amdgcn_exp2f(d * kSig);
                float g = __builtin_amdgcn_rcpf(1.f + ex);
                acc = fmaf(g, (float)(ch * 32 + tt), acc);
            }
        }
        ctxv[u] = fminf(fmaxf(acc, 0.f), (float)(MAXLEN - 2));
    }
    __syncthreads();

    // 2) emit 64 rows x 1024 cols in 32-col chunks
#pragma unroll 1
    for (int ch = 0; ch < 32; ++ch) {
        __syncthreads();
        {   // build emb rows t = ch*32 .. +32 (8 elems/thread)
            int tl = tid >> 3;
            int d0 = (tid & 7) * 8;
            float c = ctxv[ch * 32 + tl];
            int fl = (int)c;
            float fr = c - (float)fl;
            int ce = min(fl + 1, MAXLEN - 1);
#pragma unroll
            for (int e = 0; e < 8; ++e) {
                float e0 = tb[fl * DH + d0 + e];
                float e1 = tb[ce * DH + d0 + e];
                embch[tl * 64 + d0 + e] = e0 + fr * (e1 - e0);
            }
        }
        __syncthreads();
        int s = tid >> 2;
        int t0 = (tid & 3) * 8;
        const float* qr = qb + (size_t)(r0 + s) * DH;
#pragma unroll
        for (int tt = 0; tt < 8; ++tt) {
            const float* er = embch + (t0 + tt) * 64;
            float dsum = 0.f;
#pragma unroll
            for (int e = 0; e < 16; ++e) {
                const float4 qq = *reinterpret_cast<const float4*>(qr + e * 4);
                const float4 ee = *reinterpret_cast<const float4*>(er + e * 4);
                dsum += qq.x * ee.x + qq.y * ee.y + qq.z * ee.z + qq.w * ee.w;
            }
            out[((size_t)bh << 20) + (size_t)(r0 + s) * 1024 + ch * 32 + t0 + tt] =
                dsum;
        }
    }
}

extern "C" void kernel_launch(void* const* d_in, const int* in_sizes, int n_in,
                              void* d_out, int out_size, void* d_ws, size_t ws_size,
                              hipStream_t stream) {
    const float* q  = (const float*)d_in[0];
    const float* k  = (const float*)d_in[1];
    const float* tb = (const float*)d_in[2];
    float* out = (float*)d_out;

    vote_kernel<<<BH * 8, 256, 0, stream>>>(q, k, tb);
    emit_kernel<<<2048, 256, 0, stream>>>(q, k, tb, out);
}

// Round 6
// 292.438 us; speedup vs baseline: 1.0208x; 1.0208x over previous
//
#include <hip/hip_runtime.h>

#define Bb_ 4
#define Hh_ 16
#define Ss_ 1024
#define DH 64
#define MAXLEN 2048
#define BH (Bb_*Hh_)
#define LDST 72   // 64 + 8 pad (bf16 elems)

typedef __attribute__((ext_vector_type(8))) short short8;
typedef __attribute__((ext_vector_type(4))) float floatx4;
typedef __attribute__((ext_vector_type(4))) unsigned short ushort4v;

// Cross-kernel scratch as device globals: load-time allocated, graph-capture
// safe, rewritten by vote_kernel every replay before emit_kernel reads them.
__device__ int   g_flags[512];
__device__ float g_cvals[64 * 1024];

static __device__ __forceinline__ unsigned short f2bf(float f) {
    unsigned int u = __builtin_bit_cast(unsigned int, f);
    u = (u + 0x7fffu + ((u >> 16) & 1u)) >> 16;   // RNE
    return (unsigned short)u;
}

// Stage a 128x64 fp32 tile (row stride 64) -> bf16 LDS tile (row stride LDST)
static __device__ __forceinline__ void stage_tile(unsigned short* lds,
                                                  const float* __restrict__ g,
                                                  int tid) {
#pragma unroll
    for (int it = 0; it < 8; ++it) {
        int idx = it * 1024 + tid * 4;
        int row = idx >> 6, col = idx & 63;
        const float4 v = *reinterpret_cast<const float4*>(g + row * 64 + col);
        ushort4v o = { f2bf(v.x), f2bf(v.y), f2bf(v.z), f2bf(v.w) };
        *reinterpret_cast<ushort4v*>(lds + row * LDST + col) = o;
    }
}

// ===========================================================================
// R19 (consolidation): best-measured structure = R17's two-kernel split with
// per-block-contiguous emit (291.7 us), deconfounded via device globals
// (R18 proved the split executes and that store organization is NOT a lever:
// four orthogonal layouts R15-R18 all land within fill-duration noise).
// Kernel A (vote): block (bh,j) votes its 128 ctx rows against the top-32
// k rows (nonneg terms: partial >= 4096 -> ctx clips to 2046 exactly, ~10
// sigma margin vs bf16 error; failure -> exact slow path, correctness never
// at risk) and writes c[bh][s] = q[s].tb[2046].
// Kernel B (emit): 1024 blocks, 256 KB contiguous region each, pure
// full-line float4 stores at the write floor. Slow path self-contained fp32
// exact (never taken on bench data).
// ===========================================================================

__global__ __launch_bounds__(256, 2)
void vote_kernel(const float* __restrict__ q, const float* __restrict__ k,
                 const float* __restrict__ tb) {
    __shared__ __align__(16) unsigned short Ab[128 * LDST];
    __shared__ __align__(16) unsigned short Kb[32 * LDST];
    __shared__ __align__(16) float sh_pr[64];
    __shared__ int shf[4];

    int bx = blockIdx.x;
    int bh = bx >> 3, j = bx & 7;
    int tid = threadIdx.x;
    int lane = tid & 63, w = tid >> 6;
    int lo = lane & 15, quad = lane >> 4;

    const float* kb = k + (size_t)bh * Ss_ * DH;
    const float* qb = q + (size_t)bh * Ss_ * DH;
    const float kSig = -0.18033688011112042f;  // -(1/8)*log2(e)

    {   // stage k rows [992,1024) -> Kb
        const float* ktop = kb + (size_t)992 * DH;
#pragma unroll
        for (int it = 0; it < 2; ++it) {
            int idx = it * 1024 + tid * 4;
            int row = idx >> 6, col = idx & 63;
            const float4 v = *reinterpret_cast<const float4*>(ktop + row * 64 + col);
            ushort4v o = { f2bf(v.x), f2bf(v.y), f2bf(v.z), f2bf(v.w) };
            *reinterpret_cast<ushort4v*>(Kb + row * LDST + col) = o;
        }
    }
    stage_tile(Ab, qb + (size_t)j * 128 * DH, tid);
    if (tid < 16) {
        int d0 = tid * 4;
        *reinterpret_cast<float4*>(&sh_pr[d0]) =
            *reinterpret_cast<const float4*>(tb + (size_t)(MAXLEN - 2) * DH + d0);
    }
    __syncthreads();

    short8 bkr[2][2];
#pragma unroll
    for (int j2 = 0; j2 < 2; ++j2) {
        bkr[j2][0] = *reinterpret_cast<const short8*>(
            &Kb[(j2 * 16 + lo) * LDST + 0 + quad * 8]);
        bkr[j2][1] = *reinterpret_cast<const short8*>(
            &Kb[(j2 * 16 + lo) * LDST + 32 + quad * 8]);
    }
    short8 afr[2][2];
#pragma unroll
    for (int i = 0; i < 2; ++i)
#pragma unroll
        for (int k2 = 0; k2 < 2; ++k2)
            afr[i][k2] = *reinterpret_cast<const short8*>(
                &Ab[(w * 32 + i * 16 + lo) * LDST + k2 * 32 + quad * 8]);

    float ps[2][4];
#pragma unroll
    for (int i = 0; i < 2; ++i)
#pragma unroll
        for (int r = 0; r < 4; ++r) ps[i][r] = 0.f;

#pragma unroll
    for (int j2 = 0; j2 < 2; ++j2) {
        float tcol = (float)(992 + j2 * 16 + lo);
#pragma unroll
        for (int i = 0; i < 2; ++i) {
            floatx4 c = {0.f, 0.f, 0.f, 0.f};
            c = __builtin_amdgcn_mfma_f32_16x16x32_bf16(afr[i][0], bkr[j2][0], c, 0, 0, 0);
            c = __builtin_amdgcn_mfma_f32_16x16x32_bf16(afr[i][1], bkr[j2][1], c, 0, 0, 0);
#pragma unroll
            for (int r = 0; r < 4; ++r) {
                float e = __builtin_amdgcn_exp2f(c[r] * kSig);
                float g = __builtin_amdgcn_rcpf(1.0f + e);
                ps[i][r] = fmaf(g, tcol, ps[i][r]);
            }
        }
    }

    bool ok = true;
#pragma unroll
    for (int i = 0; i < 2; ++i)
#pragma unroll
        for (int r = 0; r < 4; ++r) {
            float v = ps[i][r];
            v += __shfl_xor(v, 1);
            v += __shfl_xor(v, 2);
            v += __shfl_xor(v, 4);
            v += __shfl_xor(v, 8);
            ok = ok && (v >= 4096.0f);   // margin over 2046 vs bf16 error
        }
    int wall = __all(ok);
    if (lane == 0) shf[w] = wall;
    __syncthreads();
    if (tid == 0) g_flags[bx] = (shf[0] & shf[1] & shf[2] & shf[3]) & 1;

    // per-row constants c = q[row].e2046 (fp32, bit-identical to R16-R18)
    {
        int half = tid & 1;
        float ph[32];
#pragma unroll
        for (int d = 0; d < 32; ++d) ph[d] = sh_pr[half * 32 + d];
        int row = tid >> 1;
        const float* qr = qb + (size_t)(j * 128 + row) * DH + half * 32;
        float s = 0.f;
#pragma unroll
        for (int d = 0; d < 32; d += 4) {
            const float4 qq = *reinterpret_cast<const float4*>(qr + d);
            s += qq.x * ph[d] + qq.y * ph[d + 1] + qq.z * ph[d + 2] +
                 qq.w * ph[d + 3];
        }
        s += __shfl_xor(s, 1);
        if (half == 0) g_cvals[(bh << 10) + j * 128 + row] = s;
    }
}

__global__ __launch_bounds__(256, 4)
void emit_kernel(const float* __restrict__ q, const float* __restrict__ k,
                 const float* __restrict__ tb, float* __restrict__ out) {
    __shared__ __align__(16) float sh[5120];  // 20 KB: slow path only
    __shared__ float shc[64];
    __shared__ int wok[4];
    float* kch   = sh;            // 2048 f: 32x64 k chunk
    float* embch = sh + 2048;     // 2048 f: 32x64 emb chunk
    float* ctxv  = sh + 4096;     // 1024 f: ctx

    int bx = blockIdx.x;
    int bh = bx >> 4, m = bx & 15;
    int tid = threadIdx.x;
    int lane = tid & 63, w = tid >> 6;
    int r0 = m * 64;

    // hoist cvals load ahead of flag-dependent branch (overlaps latency)
    if (tid < 64) shc[tid] = g_cvals[(bh << 10) + r0 + tid];

    // device-wide fast/slow decision (uniform: all blocks read same flags)
    int myok = g_flags[tid] & g_flags[tid + 256];
    unsigned long long bl = __ballot(myok != 0);
    if (lane == 0) wok[w] = (bl == ~0ull) ? 1 : 0;
    __syncthreads();
    int fast = wok[0] & wok[1] & wok[2] & wok[3];

    float* po = out + ((size_t)bh << 20) + ((size_t)r0 << 10) + tid * 4;

    if (fast) {
        // Contiguous 256 KB region, one full 4 KB row per iteration.
#pragma unroll 8
        for (int i = 0; i < 64; ++i) {
            float c = shc[i];
            floatx4 vv = {c, c, c, c};
            *reinterpret_cast<floatx4*>(po + (size_t)i * 1024) = vv;
        }
        return;
    }

    // ---- SLOW (exact; not taken on bench data): self-contained ----------
    const float* qb = q + (size_t)bh * Ss_ * DH;
    const float* kb = k + (size_t)bh * Ss_ * DH;
    const float kSig = -0.18033688011112042f;

    // 1) ctx[u] for ALL 1024 u, fp32 exact
#pragma unroll 1
    for (int p = 0; p < 4; ++p) {
        int u = p * 256 + tid;
        float4 qr[16];
#pragma unroll
        for (int d = 0; d < 16; ++d)
            qr[d] = *reinterpret_cast<const float4*>(qb + (size_t)u * DH + d * 4);
        float acc = 0.f;
#pragma unroll 1
        for (int ch = 0; ch < 32; ++ch) {
            __syncthreads();
            {
                int idx = tid * 8;
                const float4 a = *reinterpret_cast<const float4*>(
                    kb + (size_t)ch * 32 * DH + idx);
                const float4 b = *reinterpret_cast<const float4*>(
                    kb + (size_t)ch * 32 * DH + idx + 4);
                *reinterpret_cast<float4*>(kch + idx) = a;
                *reinterpret_cast<float4*>(kch + idx + 4) = b;
            }
            __syncthreads();
#pragma unroll
            for (int tt = 0; tt < 32; ++tt) {
                const float* kr = kch + tt * 64;
                float d = 0.f;
#pragma unroll
                for (int e = 0; e < 16; ++e) {
                    const float4 kk = *reinterpret_cast<const float4*>(kr + e * 4);
                    d += qr[e].x * kk.x + qr[e].y * kk.y + qr[e].z * kk.z +
                         qr[e].w * kk.w;
                }
                float ex = __builtin_amdgcn_exp2f(d * kSig);
                float g = __builtin_amdgcn_rcpf(1.f + ex);
                acc = fmaf(g, (float)(ch * 32 + tt), acc);
            }
        }
        ctxv[u] = fminf(fmaxf(acc, 0.f), (float)(MAXLEN - 2));
    }
    __syncthreads();

    // 2) emit 64 rows x 1024 cols in 32-col chunks
#pragma unroll 1
    for (int ch = 0; ch < 32; ++ch) {
        __syncthreads();
        {   // build emb rows t = ch*32 .. +32 (8 elems/thread)
            int tl = tid >> 3;
            int d0 = (tid & 7) * 8;
            float c = ctxv[ch * 32 + tl];
            int fl = (int)c;
            float fr = c - (float)fl;
            int ce = min(fl + 1, MAXLEN - 1);
#pragma unroll
            for (int e = 0; e < 8; ++e) {
                float e0 = tb[fl * DH + d0 + e];
                float e1 = tb[ce * DH + d0 + e];
                embch[tl * 64 + d0 + e] = e0 + fr * (e1 - e0);
            }
        }
        __syncthreads();
        int s = tid >> 2;
        int t0 = (tid & 3) * 8;
        const float* qr = qb + (size_t)(r0 + s) * DH;
#pragma unroll
        for (int tt = 0; tt < 8; ++tt) {
            const float* er = embch + (t0 + tt) * 64;
            float dsum = 0.f;
#pragma unroll
            for (int e = 0; e < 16; ++e) {
                const float4 qq = *reinterpret_cast<const float4*>(qr + e * 4);
                const float4 ee = *reinterpret_cast<const float4*>(er + e * 4);
                dsum += qq.x * ee.x + qq.y * ee.y + qq.z * ee.z + qq.w * ee.w;
            }
            out[((size_t)bh << 20) + (size_t)(r0 + s) * 1024 + ch * 32 + t0 + tt] =
                dsum;
        }
    }
}

extern "C" void kernel_launch(void* const* d_in, const int* in_sizes, int n_in,
                              void* d_out, int out_size, void* d_ws, size_t ws_size,
                              hipStream_t stream) {
    const float* q  = (const float*)d_in[0];
    const float* k  = (const float*)d_in[1];
    const float* tb = (const float*)d_in[2];
    float* out = (float*)d_out;

    vote_kernel<<<BH * 8, 256, 0, stream>>>(q, k, tb);
    emit_kernel<<<1024, 256, 0, stream>>>(q, k, tb, out);
}